// Round 15
// baseline (183.214 us; speedup 1.0000x reference)
//
#include <hip/hip_runtime.h>

// Round 15: 2 independent blocks/CU -> true 2 waves/SIMD.
// Grid 512 x 256thr. Block = 32q: 4 waves = 2 qw(16q) x 2 g(2048-key split-K).
// K: LDS 4-buffer ring, staged 2 tiles ahead via gl16, 1 barrier/16-key tile
// (only 4 waves per barrier domain; 2 anti-phase blocks/CU). V: registers,
// single-buffered per 32-key group. PV 16x16x32 (K=32). Softmax per 32 keys,
// shuffle-free common path (defer-max local check). launch_bounds(256,2).
//   d_in: 0=x f32, 1=mask i32, 2=Wk, 3=Wq, 4=Wv
// ws (f16): qT [BT/32][8192] | kT [BT/16][4096] | vT [BT/32][8192]
//   qT: [(qh*8+kc)*512 + l4*128 + tok*8 + j]  (x1/16 folded)
//   kT: [kc*512 + ch*128 + key*8 + j]     <-> K[16t+key][kc*32+ch*8+j]
//   vT: [grp][dt*512 + c*128 + d16*8 + j] <-> V^T[dt*16+d16][32grp+c*8+j]

typedef __attribute__((ext_vector_type(8)))  _Float16 f16x8;
typedef __attribute__((ext_vector_type(4)))  _Float16 f16x4;
typedef __attribute__((ext_vector_type(4)))  float    f32x4;

constexpr int Bb = 4;
constexpr int Tt = 4096;
constexpr int Cc = 256;
constexpr int BT = Bb * Tt;

#define MFMA16(a, b, c) __builtin_amdgcn_mfma_f32_16x16x32_f16((a), (b), (c), 0, 0, 0)

__device__ __forceinline__ void gl16(const _Float16* gp, char* lp) {
    __builtin_amdgcn_global_load_lds(
        (const __attribute__((address_space(1))) void*)gp,
        (__attribute__((address_space(3))) void*)lp, 16, 0, 0);
}

// ---------------- Kernel A: fused QKV projection ----------------
__global__ __launch_bounds__(256) void qkv_proj(
    const float* __restrict__ x,
    const float* __restrict__ Wq, const float* __restrict__ Wk,
    const float* __restrict__ Wv,
    _Float16* __restrict__ qo, _Float16* __restrict__ ko,
    _Float16* __restrict__ vto)
{
    extern __shared__ _Float16 sm[];
    _Float16* xs = sm;              // [128][264]
    _Float16* wsm = sm + 128 * 264; // [128][264]

    const int tid = threadIdx.x;
    const int m0  = blockIdx.x * 128;
    const int ny  = blockIdx.y;
    const int mat = ny >> 1;              // 0=q 1=k 2=v
    const int d0  = (ny & 1) * 128;
    const float* W = (mat == 0) ? Wq : (mat == 1 ? Wk : Wv);

#pragma unroll
    for (int i = 0; i < 32; ++i) {
        int flat = i * 256 + tid;
        int r = flat >> 6, c4 = (flat & 63) << 2;
        float4 v = *reinterpret_cast<const float4*>(x + (size_t)(m0 + r) * Cc + c4);
        f16x4 h = { (_Float16)v.x, (_Float16)v.y, (_Float16)v.z, (_Float16)v.w };
        *reinterpret_cast<f16x4*>(xs + r * 264 + c4) = h;
    }
#pragma unroll
    for (int i = 0; i < 32; ++i) {
        int flat = i * 256 + tid;
        int r = flat >> 6, c4 = (flat & 63) << 2;
        float4 v = *reinterpret_cast<const float4*>(W + (size_t)(d0 + r) * Cc + c4);
        f16x4 h = { (_Float16)v.x, (_Float16)v.y, (_Float16)v.z, (_Float16)v.w };
        *reinterpret_cast<f16x4*>(wsm + r * 264 + c4) = h;
    }
    __syncthreads();

    const int w = tid >> 6, lane = tid & 63;
    const int lr = lane & 15, lg = lane >> 4;

    f32x4 acc[2][8] = {};

#pragma unroll
    for (int kc = 0; kc < 8; ++kc) {
        const int c0 = kc * 32 + lg * 8;
        f16x8 xf[2], wf[8];
#pragma unroll
        for (int mb = 0; mb < 2; ++mb)
            xf[mb] = *reinterpret_cast<const f16x8*>(xs + (w * 32 + mb * 16 + lr) * 264 + c0);
#pragma unroll
        for (int db = 0; db < 8; ++db)
            wf[db] = *reinterpret_cast<const f16x8*>(wsm + (db * 16 + lr) * 264 + c0);
        if (mat != 2) {
#pragma unroll
            for (int mb = 0; mb < 2; ++mb)
#pragma unroll
                for (int db = 0; db < 8; ++db)
                    acc[mb][db] = MFMA16(wf[db], xf[mb], acc[mb][db]);   // D[d][tok]
        } else {
#pragma unroll
            for (int mb = 0; mb < 2; ++mb)
#pragma unroll
                for (int db = 0; db < 8; ++db)
                    acc[mb][db] = MFMA16(xf[mb], wf[db], acc[mb][db]);   // D[tok][d]
        }
    }

    if (mat != 2) {
        const float sc = (mat == 0) ? 0.0625f : 1.0f;
        const int jj  = (lg & 1) * 4;
#pragma unroll
        for (int mb = 0; mb < 2; ++mb)
#pragma unroll
            for (int db = 0; db < 8; ++db) {
                int m  = m0 + w * 32 + mb * 16 + lr;
                int c  = d0 + db * 16 + lg * 4;
                int kc = c >> 5;
                int ch = (c >> 3) & 3;
                f32x4 a = acc[mb][db];
                f16x4 h = { (_Float16)(a.x * sc), (_Float16)(a.y * sc),
                            (_Float16)(a.z * sc), (_Float16)(a.w * sc) };
                if (mat == 0) {
                    size_t off = (size_t)(m >> 5) * 8192 + (((m >> 4) & 1) * 8 + kc) * 512
                               + ch * 128 + (m & 15) * 8 + jj;
                    *reinterpret_cast<f16x4*>(qo + off) = h;
                } else {
                    size_t off = (size_t)(m >> 4) * 4096 + kc * 512
                               + ch * 128 + (m & 15) * 8 + jj;
                    *reinterpret_cast<f16x4*>(ko + off) = h;
                }
            }
    } else {
        // vT: [grp=m>>5][dt=d>>4][c=(m&31)>>3][d&15][m&7]; keys m..m+3 -> j run
#pragma unroll
        for (int mb = 0; mb < 2; ++mb)
#pragma unroll
            for (int db = 0; db < 8; ++db) {
                int d = d0 + db * 16 + lr;
                int m = m0 + w * 32 + mb * 16 + lg * 4;
                f32x4 a = acc[mb][db];
                f16x4 h = { (_Float16)a.x, (_Float16)a.y, (_Float16)a.z, (_Float16)a.w };
                size_t off = (size_t)(m >> 5) * 8192 + (size_t)(d >> 4) * 512
                           + ((m & 31) >> 3) * 128 + (d & 15) * 8 + (m & 7);
                *reinterpret_cast<f16x4*>(vto + off) = h;
            }
    }
}

// ---------------- Kernel B: flash attention, 2 blocks/CU ----------------
// LDS (bytes): [0,65536) ksm [2 g][4 buf][8KB] | [65536,70656) P [4][16][40] f16
//              [70656,70912) mex f32[4][16] | [70912,71168) lex
// epilogue oex f32[32][258] overlays [0,33024)
__global__ __launch_bounds__(256, 2) void attn_kernel(
    const _Float16* __restrict__ qb, const _Float16* __restrict__ kb,
    const _Float16* __restrict__ vtb, const int* __restrict__ mask,
    float* __restrict__ outp)
{
    extern __shared__ char smraw[];
    float* mex  = (float*)(smraw + 70656);
    float* lex  = (float*)(smraw + 70912);
    float* oexf = (float*)smraw;

    const int tid = threadIdx.x, w = tid >> 6, lane = tid & 63;
    const int qw = w >> 1, g = w & 1;
    const int l15 = lane & 15, l4 = lane >> 4;

    const int bid = blockIdx.x;
    const int b   = (bid & 7) >> 1;                    // batch -> XCD pair
    const int qt  = ((bid >> 3) << 1) | (bid & 1);     // [0,128)
    const int q0  = qt * 32;
    const size_t base = (size_t)b * Tt * Cc;
    const int* maskb = mask + (size_t)b * Tt;
    const _Float16* kTb = kb + base;
    const _Float16* vTb = vtb + base;

    // Q fragments: Q[q0 + qw*16 + l15][kc*32 + l4*8 + j]  (x1/16 folded)
    f16x8 qf[8];
    {
        const _Float16* qTb = qb + (size_t)(b * 128 + qt) * 8192;
#pragma unroll
        for (int kc = 0; kc < 8; ++kc)
            qf[kc] = *reinterpret_cast<const f16x8*>(
                qTb + (qw * 8 + kc) * 512 + l4 * 128 + l15 * 8);
    }

    _Float16* pw = (_Float16*)(smraw + 65536) + w * 640;   // [16][40]
    char* kslab = smraw + g * 32768;                       // [4 buf][8KB]

    f32x4 o[16] = {};                  // O^T[d = dt*16 + l4*4 + r][q = l15]
    float m_run = -60.f, l_run = 0.f;

    // K stage: 2 waves per g each stage half a tile (4 gl16 of 1KB)
    auto STAGE_K = [&](int t, int buf) {
        char* dst = kslab + buf * 8192 + qw * 4096;
        const _Float16* src = kTb + (size_t)(g * 128 + t) * 4096 + qw * 2048 + lane * 8;
#pragma unroll
        for (int j = 0; j < 4; ++j) gl16(src + j * 512, dst + j * 1024);
    };
    // V: 32-key group -> 16 A-frags (dt 0..15) in regs
    f16x8 vf[16];
    auto LOADV = [&](int grp) {
        const _Float16* p = vTb + (size_t)(g * 64 + grp) * 8192 + l4 * 128 + l15 * 8;
#pragma unroll
        for (int dt = 0; dt < 16; ++dt)
            vf[dt] = *reinterpret_cast<const f16x8*>(p + dt * 512);
    };

    STAGE_K(0, 0);
    STAGE_K(1, 1);
    LOADV(0);

    f32x4 sa = {}, sb = {};

#pragma unroll 1
    for (int t = 0; t < 128; ++t) {
        __syncthreads();                       // K(t) ready in buf[t&3]
        if (t + 2 < 128) STAGE_K(t + 2, (t + 2) & 3);

        const _Float16* kb_ = (const _Float16*)(kslab + (t & 3) * 8192);
        int4 mc = *reinterpret_cast<const int4*>(maskb + (g * 128 + t) * 16 + l4 * 4);

        // QK: S^T[key = l4*4 + r][q = l15]
        f32x4 s = { 0.f, 0.f, 0.f, 0.f };
        __builtin_amdgcn_s_setprio(1);
#pragma unroll
        for (int kc = 0; kc < 8; ++kc) {
            f16x8 kf = *reinterpret_cast<const f16x8*>(kb_ + kc * 512 + l4 * 128 + l15 * 8);
            s = MFMA16(kf, qf[kc], s);
        }
        __builtin_amdgcn_s_setprio(0);

        if (mc.x == 0) s[0] = -1e30f;
        if (mc.y == 0) s[1] = -1e30f;
        if (mc.z == 0) s[2] = -1e30f;
        if (mc.w == 0) s[3] = -1e30f;

        if (!(t & 1)) { sa = s; continue; }
        sb = s;

        // ---- softmax over 32 keys; shuffle-free common path ----
        float tl = fmaxf(fmaxf(fmaxf(sa[0], sa[1]), fmaxf(sa[2], sa[3])),
                         fmaxf(fmaxf(sb[0], sb[1]), fmaxf(sb[2], sb[3])));
        if (__any(tl > m_run + 8.f)) {         // rare: true max + rescale
            float tm = tl;
            tm = fmaxf(tm, __shfl_xor(tm, 16, 64));
            tm = fmaxf(tm, __shfl_xor(tm, 32, 64));
            float mn = fmaxf(m_run, tm);
            float cs = __expf(m_run - mn);
            m_run = mn; l_run *= cs;
#pragma unroll
            for (int dt = 0; dt < 16; ++dt) o[dt] *= cs;
        }

        float rs = 0.f;
#pragma unroll
        for (int r = 0; r < 4; ++r) {
            float p0 = __expf(sa[r] - m_run); sa[r] = p0; rs += p0;
            float p1 = __expf(sb[r] - m_run); sb[r] = p1; rs += p1;
        }
        rs += __shfl_xor(rs, 16, 64);
        rs += __shfl_xor(rs, 32, 64);
        l_run += rs;

        // ---- P -> pw[q=l15][k 0..31] f16; reread as PV B-frag ----
        {
            f16x4 h0 = { (_Float16)sa[0], (_Float16)sa[1], (_Float16)sa[2], (_Float16)sa[3] };
            f16x4 h1 = { (_Float16)sb[0], (_Float16)sb[1], (_Float16)sb[2], (_Float16)sb[3] };
            *reinterpret_cast<f16x4*>(pw + l15 * 40 + l4 * 4)      = h0;
            *reinterpret_cast<f16x4*>(pw + l15 * 40 + 16 + l4 * 4) = h1;
        }
        f16x8 pf = *reinterpret_cast<const f16x8*>(pw + l15 * 40 + l4 * 8);

        // ---- PV: O^T += V^T P^T  (16x16x32, K = 32 keys) ----
        __builtin_amdgcn_s_setprio(1);
#pragma unroll
        for (int dt = 0; dt < 16; ++dt)
            o[dt] = MFMA16(vf[dt], pf, o[dt]);
        __builtin_amdgcn_s_setprio(0);

        if (t + 2 < 128) LOADV((t + 1) >> 1);  // next 32-key group (WAR-safe)
    }
    __syncthreads();   // all waves done with ksm; safe to reuse as oex

    // ---- epilogue: 2-way g-merge per qw ----
    if (l4 == 0) { mex[w * 16 + l15] = m_run; lex[w * 16 + l15] = l_run; }
    __syncthreads();

    {
        float mA2 = mex[(qw * 2 + 0) * 16 + l15];
        float mB2 = mex[(qw * 2 + 1) * 16 + l15];
        float mst = fmaxf(mA2, mB2);
        float osc = __expf(m_run - mst);
        float* oq = oexf + (qw * 16 + l15) * 258;
        if (g == 1) {
#pragma unroll
            for (int dt = 0; dt < 16; ++dt) {
                f32x4 v = { o[dt][0] * osc, o[dt][1] * osc, o[dt][2] * osc, o[dt][3] * osc };
                *reinterpret_cast<f32x4*>(oq + dt * 16 + l4 * 4) = v;
            }
        }
        __syncthreads();
        if (g == 0) {
#pragma unroll
            for (int dt = 0; dt < 16; ++dt) {
                f32x4 v = *reinterpret_cast<const f32x4*>(oq + dt * 16 + l4 * 4);
                v[0] += o[dt][0] * osc; v[1] += o[dt][1] * osc;
                v[2] += o[dt][2] * osc; v[3] += o[dt][3] * osc;
                *reinterpret_cast<f32x4*>(oq + dt * 16 + l4 * 4) = v;
            }
        }
        __syncthreads();
    }

    // readout: q' = tid>>3 in [0,32), dseg = (tid&7)*32
    {
        const int qv = tid >> 3, ds0 = (tid & 7) * 32;
        const int qws = qv >> 4, ql = qv & 15;
        float mA2 = mex[(qws * 2 + 0) * 16 + ql];
        float mB2 = mex[(qws * 2 + 1) * 16 + ql];
        float ms  = fmaxf(mA2, mB2);
        float lt  = lex[(qws * 2 + 0) * 16 + ql] * __expf(mA2 - ms)
                  + lex[(qws * 2 + 1) * 16 + ql] * __expf(mB2 - ms);
        float inv = 1.f / lt;
        const float* src = oexf + qv * 258 + ds0;
        float* dst = outp + base + (size_t)(q0 + qv) * Cc + ds0;
#pragma unroll
        for (int i = 0; i < 8; ++i) {
            f32x4 a = *reinterpret_cast<const f32x4*>(src + 4 * i);
            a[0] *= inv; a[1] *= inv; a[2] *= inv; a[3] *= inv;
            *reinterpret_cast<f32x4*>(dst + 4 * i) = a;
        }
    }
}

extern "C" void kernel_launch(void* const* d_in, const int* in_sizes, int n_in,
                              void* d_out, int out_size, void* d_ws, size_t ws_size,
                              hipStream_t stream)
{
    (void)in_sizes; (void)n_in; (void)out_size; (void)ws_size;
    const float* x   = (const float*)d_in[0];
    const int*  mask = (const int*)d_in[1];
    const float* Wk  = (const float*)d_in[2];
    const float* Wq  = (const float*)d_in[3];
    const float* Wv  = (const float*)d_in[4];
    float* out = (float*)d_out;

    _Float16* q  = (_Float16*)d_ws;
    _Float16* k  = q + (size_t)BT * Cc;
    _Float16* vt = k + (size_t)BT * Cc;

    dim3 gA(128, 6), blkA(256);
    size_t ldsA = (size_t)(128 + 128) * 264 * sizeof(_Float16);
    qkv_proj<<<gA, blkA, ldsA, stream>>>(x, Wq, Wk, Wv, q, k, vt);

    dim3 gB(512), blkB(256);
    size_t ldsB = 71168;
    attn_kernel<<<gB, blkB, ldsB, stream>>>(q, k, vt, mask, out);
}